// Round 10
// baseline (350.327 us; speedup 1.0000x reference)
//
#include <hip/hip_runtime.h>
#include <hip/hip_fp16.h>
#include <math.h>

#define HW 65536               // 256*256

typedef float v2f __attribute__((ext_vector_type(2), aligned(8)));
typedef _Float16 h2 __attribute__((ext_vector_type(2)));

__device__ __forceinline__ h2 uh(unsigned u) { return __builtin_bit_cast(h2, u); }
__device__ __forceinline__ unsigned hu(h2 v) { return __builtin_bit_cast(unsigned, v); }
__device__ __forceinline__ unsigned algn(unsigned lo, unsigned hi) {
    return (lo >> 16) | (hi << 16);          // v_alignbit_b32
}

#define CEH(a, b) { h2 _t = __builtin_elementwise_min(a, b); \
                    b = __builtin_elementwise_max(a, b); a = _t; }

__device__ __forceinline__ void sort8_h2(h2* v) {
    CEH(v[0], v[1]); CEH(v[2], v[3]); CEH(v[4], v[5]); CEH(v[6], v[7]);
    CEH(v[0], v[2]); CEH(v[1], v[3]); CEH(v[4], v[6]); CEH(v[5], v[7]);
    CEH(v[1], v[2]); CEH(v[5], v[6]); CEH(v[0], v[4]); CEH(v[3], v[7]);
    CEH(v[1], v[5]); CEH(v[2], v[6]);
    CEH(v[1], v[4]); CEH(v[3], v[6]);
    CEH(v[2], v[4]); CEH(v[3], v[5]);
    CEH(v[3], v[4]);
}
__device__ __forceinline__ void sort4_h2(h2* v) {
    CEH(v[0], v[1]); CEH(v[2], v[3]); CEH(v[0], v[2]); CEH(v[1], v[3]); CEH(v[1], v[2]);
}

// ---------------- K1: in_conv 1x1 64->16 (uniform-scalar weights) + pack in block 0 ----------
// wtab layout: [0..1023] machinery per-(c,i); [1024..1087] bw; [2048+c*96..] dw weights
__global__ __launch_bounds__(256) void k_inconv(const float* __restrict__ cen,
                                                const float* __restrict__ in_w,
                                                const float* __restrict__ in_b,
                                                const float* __restrict__ l1w,
                                                const float* __restrict__ l1b,
                                                const float* __restrict__ l2w,
                                                const float* __restrict__ l2b,
                                                const float* __restrict__ bw,
                                                const float* __restrict__ dw_w1,
                                                const float* __restrict__ dw_b1,
                                                const float* __restrict__ dw_w3,
                                                const float* __restrict__ dw_b3,
                                                const float* __restrict__ dw_w5,
                                                const float* __restrict__ dw_b5,
                                                const float* __restrict__ dw_w7,
                                                const float* __restrict__ dw_b7,
                                                unsigned* __restrict__ wtab,
                                                __half* __restrict__ xh) {
    // ---- block 0: pack weights for k_fused (consumed only by the later dispatch) ----
    if (blockIdx.x == 0) {
        for (int t = threadIdx.x; t < 3584; t += 256) {
            float v = 0.f;
            if (t < 1024) {
                int c = t >> 6, i = (t >> 4) & 3, j = t & 15;
                if (j < 3)        v = l1w[i * 64 + c * 4 + j];
                else if (j == 3)  v = 2.f * l1w[i * 64 + c * 4 + 3];
                else if (j == 4)  v = l1b[i * 16 + c];
                else if (j < 13)  v = l2w[i * 128 + c * 8 + (j - 5)];
                else if (j == 13) v = l2b[i * 16 + c];
            } else if (t < 1088) {
                v = bw[t - 1024];
            } else if (t >= 2048) {
                int c = (t - 2048) / 96, j = (t - 2048) - c * 96;
                if (j < 49)       v = dw_w7[c * 49 + j];
                else if (j < 74)  v = dw_w5[c * 25 + (j - 49)];
                else if (j < 83)  v = dw_w3[c * 9 + (j - 74)];
                else if (j == 83) v = dw_w1[c];
                else if (j == 84) v = dw_b1[c];
                else if (j == 85) v = dw_b3[c];
                else if (j == 86) v = dw_b5[c];
                else if (j == 87) v = dw_b7[c];
            }
            unsigned hs = (unsigned)__half_as_ushort(__float2half(v));
            wtab[t] = hs * 0x10001u;
        }
    }

    // ---- in_conv: 2 px/thread, uniform scalar weights (s_load, K$-cached 4 KB) ----
    int pr = blockIdx.x * 256 + threadIdx.x;
    int b_ = pr >> 15;
    int hw = (pr & 32767) * 2;
    const float* src = cen + (size_t)(b_ * 64) * HW + hw;

    v2f acc[16];
#pragma unroll
    for (int o = 0; o < 16; o++) { float bv = in_b[o]; v2f t = {bv, bv}; acc[o] = t; }

#pragma unroll 8
    for (int i = 0; i < 64; i++) {
        v2f xv = *(const v2f*)(src + (size_t)i * HW);
#pragma unroll
        for (int o = 0; o < 16; o++)
            acc[o] += xv * in_w[o * 64 + i];     // uniform -> s_load
    }
    __half* dst = xh + (size_t)(b_ * 16) * HW + hw;
#pragma unroll
    for (int o = 0; o < 16; o++)
        *(__half2*)(dst + (size_t)o * HW) = __floats2half2_rn(acc[o].x, acc[o].y);
}

// ---------------- K2: FUSED ----------------
#define LXS 44           // lxh dwords/row, 42 used
#define CTS 42           // convt dwords/row, 40/41 used
#define CTP (78 * CTS)   // convt plane stride

// machinery: single base, all-constexpr non-negative offsets (fold into ds_read offset:)
template<int S, int PAD, int PL>
__device__ __forceinline__ void branch_pair(const unsigned* b3, const unsigned* wt,
                                            h2* outA, h2* outB) {
    constexpr int D0  = (7 - S) / 2 + PAD;       // even
    constexpr int TOP = PL * CTP + (7 - S) * CTS + D0;
    constexpr int MID = PL * CTP + 7 * CTS + D0;
    constexpr int BOT = PL * CTP + (7 + S) * CTS + D0;
    constexpr int L   = (S + 3) / 2;
    unsigned ut[2 * L], um[2 * L], ub[2 * L];
#pragma unroll
    for (int k = 0; k < L; k++) {
        *(uint2*)&ut[2 * k] = *(const uint2*)(b3 + TOP + 2 * k);   // ds_read_b64 offset:
        *(uint2*)&um[2 * k] = *(const uint2*)(b3 + MID + 2 * k);
        *(uint2*)&ub[2 * k] = *(const uint2*)(b3 + BOT + 2 * k);
    }
#pragma unroll
    for (int dw = 0; dw < 2; dw++) {             // pair A (px 4g,4g+1), pair B (+2,+3)
        h2 n0 = uh(ut[dw]);
        h2 n1 = uh(algn(ut[(S - 1) / 2 + dw], ut[(S + 1) / 2 + dw]));
        h2 n2 = uh(ut[S + dw]);
        h2 n7 = uh(um[dw]);
        h2 ct = uh(algn(um[(S - 1) / 2 + dw], um[(S + 1) / 2 + dw]));
        h2 n3 = uh(um[S + dw]);
        h2 n6 = uh(ub[dw]);
        h2 n5 = uh(algn(ub[(S - 1) / 2 + dw], ub[(S + 1) / 2 + dw]));
        h2 n4 = uh(ub[S + dw]);

        h2 T[8];
        T[0] = ct - n0; T[1] = ct - n1; T[2] = ct - n2; T[3] = ct - n3;
        T[4] = ct - n4; T[5] = ct - n5; T[6] = ct - n6; T[7] = ct - n7;
        h2 Sm[4];
#pragma unroll
        for (int k = 0; k < 4; k++) Sm[k] = T[k] + T[k + 4];

        h2 w10 = uh(wt[0]), w11 = uh(wt[1]), w12 = uh(wt[2]);
        h2 w13x2 = uh(wt[3]), bb1 = uh(wt[4]);

        h2 R4[4];
#pragma unroll
        for (int mm = 0; mm < 4; mm++) {
            h2 r = Sm[(mm + 2) & 3] * w12 + bb1;
            r = Sm[(mm + 3) & 3] * w11 + r;
            r = Sm[(mm + 1) & 3] * w10 + r;
            R4[mm] = r;
        }
        h2 h8[8];
#pragma unroll
        for (int k = 0; k < 8; k++)
            h8[k] = (T[(k + 4) & 7] * w13x2 + R4[k & 3]) * T[k];
        sort8_h2(h8);

        h2 acc = uh(wt[13]);
#pragma unroll
        for (int k = 0; k < 8; k++) acc += h8[k] * uh(wt[5 + k]);
        if (dw == 0) *outA = acc; else *outB = acc;
    }
}

__device__ __forceinline__ unsigned tail_px(h2* bh, const unsigned* __restrict__ wtab,
                                            int c, float bsc, float bbi) {
    sort4_h2(bh);
    h2 yv = bh[0] * uh(wtab[1024 + (c << 2)]);
#pragma unroll
    for (int k = 1; k < 4; k++) yv = bh[k] * uh(wtab[1024 + (c << 2) + k]) + yv;
    float zx = fmaf((float)yv.x, bsc, bbi);
    float zy = fmaf((float)yv.y, bsc, bbi);
    float sx = zx / (1.f + __expf(-zx));
    float sy = zy / (1.f + __expf(-zy));
    return __builtin_bit_cast(unsigned, __floats2half2_rn(sx, sy));
}

template<bool GUARD>
__device__ __forceinline__ void store_crow(unsigned* convt, int ty0, int tx0,
                                           int row, int g, const unsigned* dwc,
                                           h2 a1A, h2 a1B, h2 a3A, h2 a3B,
                                           h2 a5A, h2 a5B, h2 a7A, h2 a7B) {
    unsigned mA = 0xFFFFFFFFu, mB = 0xFFFFFFFFu;
    if (GUARD) {
        int iy = ty0 - 7 + row;
        bool rin = (unsigned)iy < 256u;
        int ix0 = tx0 - 7 + 4 * g;
        mA = (rin && (unsigned)ix0 < 256u ? 0x0000FFFFu : 0u)
           | (rin && (unsigned)(ix0 + 1) < 256u ? 0xFFFF0000u : 0u);
        mB = (rin && (unsigned)(ix0 + 2) < 256u ? 0x0000FFFFu : 0u)
           | (rin && (unsigned)(ix0 + 3) < 256u ? 0xFFFF0000u : 0u);
    }
    int o = row * CTS + 2 * g;
    uint2 s3 = {hu(a3A + uh(dwc[85])) & mA, hu(a3B + uh(dwc[85])) & mB};
    uint2 s7 = {hu(a7A + uh(dwc[87])) & mA, hu(a7B + uh(dwc[87])) & mB};
    *(uint2*)&convt[CTP + o]     = s3;
    *(uint2*)&convt[3 * CTP + o] = s7;
    convt[o + 1]                 = hu(a1A + uh(dwc[84])) & mA;
    convt[o + 2]                 = hu(a1B + uh(dwc[84])) & mB;
    convt[2 * CTP + o + 1]       = hu(a5A + uh(dwc[86])) & mA;
    convt[2 * CTP + o + 2]       = hu(a5B + uh(dwc[86])) & mB;
}

template<bool GUARD>
__device__ __forceinline__ void conv_unit(const unsigned* lxh, unsigned* convt,
                                          const unsigned* dwc, int ty0, int tx0, int tid) {
    int rp_ = tid / 20, g = tid - rp_ * 20;
    int r0 = rp_ * 2;                             // output rows r0, r0+1
    h2 z = {0, 0};
    h2 a7A0 = z, a7B0 = z, a5A0 = z, a5B0 = z, a3A0 = z, a3B0 = z, a1A0 = z, a1B0 = z;
    h2 a7A1 = z, a7B1 = z, a5A1 = z, a5B1 = z, a3A1 = z, a3B1 = z, a1A1 = z, a1B1 = z;
#pragma unroll
    for (int a = 0; a < 8; a++) {
        const unsigned* rrp = lxh + (r0 + a) * LXS + 2 * g;
        uint2 w0 = *(const uint2*)rrp;
        uint2 w1 = *(const uint2*)(rrp + 2);
        uint2 w2 = *(const uint2*)(rrp + 4);
        unsigned u0 = w0.x, u1 = w0.y, u2 = w1.x, u3 = w1.y, u4 = w2.x;
        h2 E[9] = {uh(u0), uh(algn(u0, u1)), uh(u1), uh(algn(u1, u2)),
                   uh(u2), uh(algn(u2, u3)), uh(u3), uh(algn(u3, u4)), uh(u4)};
        if (a < 7) {                              // taps for output row r0
#pragma unroll
            for (int b = 0; b < 7; b++) {
                h2 wv = uh(dwc[a * 7 + b]);
                a7A0 = E[b] * wv + a7A0;  a7B0 = E[b + 2] * wv + a7B0;
            }
            if (a >= 1 && a <= 5) {
#pragma unroll
                for (int b = 0; b < 5; b++) {
                    h2 wv = uh(dwc[49 + (a - 1) * 5 + b]);
                    a5A0 = E[b + 1] * wv + a5A0;  a5B0 = E[b + 3] * wv + a5B0;
                }
            }
            if (a >= 2 && a <= 4) {
#pragma unroll
                for (int b = 0; b < 3; b++) {
                    h2 wv = uh(dwc[74 + (a - 2) * 3 + b]);
                    a3A0 = E[b + 2] * wv + a3A0;  a3B0 = E[b + 4] * wv + a3B0;
                }
            }
            if (a == 3) {
                h2 wv = uh(dwc[83]);
                a1A0 = E[3] * wv;  a1B0 = E[5] * wv;
            }
        }
        if (a >= 1) {                             // taps for output row r0+1
            const int ar = a - 1;
#pragma unroll
            for (int b = 0; b < 7; b++) {
                h2 wv = uh(dwc[ar * 7 + b]);
                a7A1 = E[b] * wv + a7A1;  a7B1 = E[b + 2] * wv + a7B1;
            }
            if (ar >= 1 && ar <= 5) {
#pragma unroll
                for (int b = 0; b < 5; b++) {
                    h2 wv = uh(dwc[49 + (ar - 1) * 5 + b]);
                    a5A1 = E[b + 1] * wv + a5A1;  a5B1 = E[b + 3] * wv + a5B1;
                }
            }
            if (ar >= 2 && ar <= 4) {
#pragma unroll
                for (int b = 0; b < 3; b++) {
                    h2 wv = uh(dwc[74 + (ar - 2) * 3 + b]);
                    a3A1 = E[b + 2] * wv + a3A1;  a3B1 = E[b + 4] * wv + a3B1;
                }
            }
            if (ar == 3) {
                h2 wv = uh(dwc[83]);
                a1A1 = E[3] * wv;  a1B1 = E[5] * wv;
            }
        }
    }
    store_crow<GUARD>(convt, ty0, tx0, r0,     g, dwc, a1A0, a1B0, a3A0, a3B0, a5A0, a5B0, a7A0, a7B0);
    store_crow<GUARD>(convt, ty0, tx0, r0 + 1, g, dwc, a1A1, a1B1, a3A1, a3B1, a5A1, a5B1, a7A1, a7B1);
}

__global__ __launch_bounds__(1024, 8) void k_fused(const __half* __restrict__ xh,
    const unsigned* __restrict__ wtab,
    const float* __restrict__ bns, const float* __restrict__ bnb,
    __half* __restrict__ y16) {

    const int by  = blockIdx.y;                  // b*16 + c
    const int c   = by & 15;
    const int ty0 = (blockIdx.x >> 2) * 64;
    const int tx0 = (blockIdx.x & 3) * 64;
    const int tid = threadIdx.x;
    // interior tile: halo [ty0-10, ty0+73] x [tx0-10, tx0+73] fully inside [0,256)
    const bool interior = (ty0 != 0) && (ty0 != 192) && (tx0 != 0) && (tx0 != 192);

    __shared__ __align__(16) unsigned lxh[84 * LXS];    // fp16 x-tile, rows ty0-10..+73
    __shared__ __align__(16) unsigned convt[4 * CTP];   // conv planes, rows ty0-7..+70

    // ---- stage: 84 rows x 21 uint2 (b64 LDS writes) ----
    {
        const unsigned* xp32 = (const unsigned*)(xh + (size_t)by * HW);
        if (interior) {
#pragma unroll
            for (int it = 0; it < 2; it++) {
                int t = tid + it * 1024;
                if (it == 0 || t < 84 * 21) {
                    int r = t / 21, j = t - r * 21;
                    const unsigned* rp = xp32 + ((ty0 - 10 + r) << 7) + ((tx0 - 10) >> 1) + 2 * j;
                    uint2 st = {rp[0], rp[1]};
                    *(uint2*)&lxh[r * LXS + 2 * j] = st;
                }
            }
        } else {
#pragma unroll
            for (int it = 0; it < 2; it++) {
                int t = tid + it * 1024;
                if (it == 0 || t < 84 * 21) {
                    int r = t / 21, j = t - r * 21;
                    int gy = ty0 - 10 + r;
                    int gp = tx0 - 10 + 4 * j;
                    unsigned v0 = 0, v1 = 0;
                    if ((unsigned)gy < 256u) {
                        const unsigned* rp = xp32 + (gy << 7);
                        if ((unsigned)gp < 256u)       v0 = rp[gp >> 1];
                        if ((unsigned)(gp + 2) < 256u) v1 = rp[(gp >> 1) + 1];
                    }
                    uint2 st = {v0, v1};
                    *(uint2*)&lxh[r * LXS + 2 * j] = st;
                }
            }
        }
    }
    __syncthreads();

    // ---- depthwise convs: 39 row-pairs x 20 col-groups = 780 units, single pass ----
    {
        const unsigned* dwc = wtab + 2048 + c * 96;   // block-uniform -> s_load
        if (tid < 780) {
            if (interior) conv_unit<false>(lxh, convt, dwc, ty0, tx0, tid);
            else          conv_unit<true>(lxh, convt, dwc, ty0, tx0, tid);
        }
    }
    __syncthreads();

    // ---- machinery: one 4-px group per thread, single-base constexpr-offset reads ----
    const int R = tid >> 4;                      // 0..63
    const int g = tid & 15;                      // px 4g..4g+3
    const unsigned* b3 = convt + R * CTS + 2 * g;

    h2 bhA[4], bhB[4];
    branch_pair<1, 1, 0>(b3, wtab + ((c << 2) + 0) * 16, &bhA[0], &bhB[0]);
    branch_pair<3, 0, 1>(b3, wtab + ((c << 2) + 1) * 16, &bhA[1], &bhB[1]);
    branch_pair<5, 1, 2>(b3, wtab + ((c << 2) + 2) * 16, &bhA[2], &bhB[2]);
    branch_pair<7, 0, 3>(b3, wtab + ((c << 2) + 3) * 16, &bhA[3], &bhB[3]);

    const float bsc = bns[c], bbi = bnb[c];
    unsigned r0 = tail_px(bhA, wtab, c, bsc, bbi);
    unsigned r1 = tail_px(bhB, wtab, c, bsc, bbi);
    uint2 st = {r0, r1};
    *(uint2*)&y16[(size_t)by * HW + (ty0 + R) * 256 + tx0 + 4 * g] = st;
}

// ---------------- K3: final 1x1 16 -> 1 + sigmoid, 4 px/thread (unchanged) ----------------
__global__ __launch_bounds__(256) void k_final(const __half* __restrict__ y16,
                                               const float* __restrict__ fw,
                                               const float* __restrict__ fb,
                                               float* __restrict__ out) {
    long t  = (long)blockIdx.x * 256 + threadIdx.x;
    long p0 = t * 4;
    int  b  = (int)(p0 >> 16);
    int  hw = (int)(p0 & 65535);

    float bv = fb[0];
    float a0 = bv, a1 = bv, a2 = bv, a3 = bv;
#pragma unroll
    for (int cc = 0; cc < 16; cc++) {
        uint2 u = *(const uint2*)(y16 + (size_t)(b * 16 + cc) * HW + hw);
        float2 v0 = __half22float2(__builtin_bit_cast(__half2, u.x));
        float2 v1 = __half22float2(__builtin_bit_cast(__half2, u.y));
        float wv = fw[cc];
        a0 = fmaf(v0.x, wv, a0);
        a1 = fmaf(v0.y, wv, a1);
        a2 = fmaf(v1.x, wv, a2);
        a3 = fmaf(v1.y, wv, a3);
    }
    float4 r;
    r.x = 1.f / (1.f + __expf(-a0));
    r.y = 1.f / (1.f + __expf(-a1));
    r.z = 1.f / (1.f + __expf(-a2));
    r.w = 1.f / (1.f + __expf(-a3));
    *(float4*)(out + p0) = r;
}

extern "C" void kernel_launch(void* const* d_in, const int* in_sizes, int n_in,
                              void* d_out, int out_size, void* d_ws, size_t ws_size,
                              hipStream_t stream) {
    (void)in_sizes; (void)n_in; (void)out_size; (void)ws_size;
    const float* cen   = (const float*)d_in[0];
    // d_in[1] = mas (unused by the reference)
    const float* in_w  = (const float*)d_in[2];
    const float* in_b  = (const float*)d_in[3];
    const float* dw_w1 = (const float*)d_in[4];
    const float* dw_b1 = (const float*)d_in[5];
    const float* dw_w3 = (const float*)d_in[6];
    const float* dw_b3 = (const float*)d_in[7];
    const float* dw_w5 = (const float*)d_in[8];
    const float* dw_b5 = (const float*)d_in[9];
    const float* dw_w7 = (const float*)d_in[10];
    const float* dw_b7 = (const float*)d_in[11];
    const float* l1w   = (const float*)d_in[12];
    const float* l1b   = (const float*)d_in[13];
    const float* l2w   = (const float*)d_in[14];
    const float* l2b   = (const float*)d_in[15];
    const float* bw    = (const float*)d_in[16];
    const float* bns   = (const float*)d_in[17];
    const float* bnb   = (const float*)d_in[18];
    const float* fw    = (const float*)d_in[19];
    const float* fb    = (const float*)d_in[20];

    // workspace: xh (16.78 MB) | wtab (16 KB) | y16 (16.78 MB)
    __half*   xh   = (__half*)d_ws;
    unsigned* wtab = (unsigned*)((char*)d_ws + (size_t)16777216);
    __half*   y16  = (__half*)((char*)d_ws + (size_t)16777216 + 16384);
    float*    out  = (float*)d_out;

    k_inconv<<<1024, 256, 0, stream>>>(cen, in_w, in_b,
                                       l1w, l1b, l2w, l2b, bw,
                                       dw_w1, dw_b1, dw_w3, dw_b3,
                                       dw_w5, dw_b5, dw_w7, dw_b7, wtab, xh);
    k_fused<<<dim3(16, 128), 1024, 0, stream>>>(xh, wtab, bns, bnb, y16);
    k_final<<<512, 256, 0, stream>>>(y16, fw, fb, out);
}

// Round 11
// 318.720 us; speedup vs baseline: 1.0992x; 1.0992x over previous
//
#include <hip/hip_runtime.h>
#include <hip/hip_fp16.h>
#include <math.h>

#define HW 65536               // 256*256

typedef float v2f __attribute__((ext_vector_type(2), aligned(8)));
typedef _Float16 h2 __attribute__((ext_vector_type(2)));

__device__ __forceinline__ h2 uh(unsigned u) { return __builtin_bit_cast(h2, u); }
__device__ __forceinline__ unsigned hu(h2 v) { return __builtin_bit_cast(unsigned, v); }
__device__ __forceinline__ unsigned algn(unsigned lo, unsigned hi) {
    return (lo >> 16) | (hi << 16);          // v_alignbit_b32
}

#define CEH(a, b) { h2 _t = __builtin_elementwise_min(a, b); \
                    b = __builtin_elementwise_max(a, b); a = _t; }

__device__ __forceinline__ void sort8_h2(h2* v) {
    CEH(v[0], v[1]); CEH(v[2], v[3]); CEH(v[4], v[5]); CEH(v[6], v[7]);
    CEH(v[0], v[2]); CEH(v[1], v[3]); CEH(v[4], v[6]); CEH(v[5], v[7]);
    CEH(v[1], v[2]); CEH(v[5], v[6]); CEH(v[0], v[4]); CEH(v[3], v[7]);
    CEH(v[1], v[5]); CEH(v[2], v[6]);
    CEH(v[1], v[4]); CEH(v[3], v[6]);
    CEH(v[2], v[4]); CEH(v[3], v[5]);
    CEH(v[3], v[4]);
}
__device__ __forceinline__ void sort4_h2(h2* v) {
    CEH(v[0], v[1]); CEH(v[2], v[3]); CEH(v[0], v[2]); CEH(v[1], v[3]); CEH(v[1], v[2]);
}

// ---------------- K1: in_conv 1x1 64->16 (uniform-scalar weights) + pack in block 0 ----------
// wtab layout: [0..1023] machinery per-(c,i); [1024..1087] bw; [2048+c*96..] dw weights
__global__ __launch_bounds__(256) void k_inconv(const float* __restrict__ cen,
                                                const float* __restrict__ in_w,
                                                const float* __restrict__ in_b,
                                                const float* __restrict__ l1w,
                                                const float* __restrict__ l1b,
                                                const float* __restrict__ l2w,
                                                const float* __restrict__ l2b,
                                                const float* __restrict__ bw,
                                                const float* __restrict__ dw_w1,
                                                const float* __restrict__ dw_b1,
                                                const float* __restrict__ dw_w3,
                                                const float* __restrict__ dw_b3,
                                                const float* __restrict__ dw_w5,
                                                const float* __restrict__ dw_b5,
                                                const float* __restrict__ dw_w7,
                                                const float* __restrict__ dw_b7,
                                                unsigned* __restrict__ wtab,
                                                __half* __restrict__ xh) {
    // ---- block 0: pack weights for k_fused (consumed only by the later dispatch) ----
    if (blockIdx.x == 0) {
        for (int t = threadIdx.x; t < 3584; t += 256) {
            float v = 0.f;
            if (t < 1024) {
                int c = t >> 6, i = (t >> 4) & 3, j = t & 15;
                if (j < 3)        v = l1w[i * 64 + c * 4 + j];
                else if (j == 3)  v = 2.f * l1w[i * 64 + c * 4 + 3];
                else if (j == 4)  v = l1b[i * 16 + c];
                else if (j < 13)  v = l2w[i * 128 + c * 8 + (j - 5)];
                else if (j == 13) v = l2b[i * 16 + c];
            } else if (t < 1088) {
                v = bw[t - 1024];
            } else if (t >= 2048) {
                int c = (t - 2048) / 96, j = (t - 2048) - c * 96;
                if (j < 49)       v = dw_w7[c * 49 + j];
                else if (j < 74)  v = dw_w5[c * 25 + (j - 49)];
                else if (j < 83)  v = dw_w3[c * 9 + (j - 74)];
                else if (j == 83) v = dw_w1[c];
                else if (j == 84) v = dw_b1[c];
                else if (j == 85) v = dw_b3[c];
                else if (j == 86) v = dw_b5[c];
                else if (j == 87) v = dw_b7[c];
            }
            unsigned hs = (unsigned)__half_as_ushort(__float2half(v));
            wtab[t] = hs * 0x10001u;
        }
    }

    // ---- in_conv: 2 px/thread, uniform scalar weights (s_load, K$-cached 4 KB) ----
    int pr = blockIdx.x * 256 + threadIdx.x;
    int b_ = pr >> 15;
    int hw = (pr & 32767) * 2;
    const float* src = cen + (size_t)(b_ * 64) * HW + hw;

    v2f acc[16];
#pragma unroll
    for (int o = 0; o < 16; o++) { float bv = in_b[o]; v2f t = {bv, bv}; acc[o] = t; }

#pragma unroll 8
    for (int i = 0; i < 64; i++) {
        v2f xv = *(const v2f*)(src + (size_t)i * HW);
#pragma unroll
        for (int o = 0; o < 16; o++)
            acc[o] += xv * in_w[o * 64 + i];     // uniform -> s_load
    }
    __half* dst = xh + (size_t)(b_ * 16) * HW + hw;
#pragma unroll
    for (int o = 0; o < 16; o++)
        *(__half2*)(dst + (size_t)o * HW) = __floats2half2_rn(acc[o].x, acc[o].y);
}

// ---------------- K2: FUSED (exact R9 version: 87 us, VGPR 24, no spill) ----------------
#define LXS 44           // lxh dwords/row, 42 used
#define CTS 42           // convt dwords/row, 40/41 used
#define CTP (78 * CTS)   // convt plane stride

// machinery: single base, all-constexpr non-negative offsets (fold into ds_read offset:)
template<int S, int PAD, int PL>
__device__ __forceinline__ void branch_pair(const unsigned* b3, const unsigned* wt,
                                            h2* outA, h2* outB) {
    constexpr int D0  = (7 - S) / 2 + PAD;       // even
    constexpr int TOP = PL * CTP + (7 - S) * CTS + D0;
    constexpr int MID = PL * CTP + 7 * CTS + D0;
    constexpr int BOT = PL * CTP + (7 + S) * CTS + D0;
    constexpr int L   = (S + 3) / 2;
    unsigned ut[2 * L], um[2 * L], ub[2 * L];
#pragma unroll
    for (int k = 0; k < L; k++) {
        *(uint2*)&ut[2 * k] = *(const uint2*)(b3 + TOP + 2 * k);   // ds_read_b64 offset:
        *(uint2*)&um[2 * k] = *(const uint2*)(b3 + MID + 2 * k);
        *(uint2*)&ub[2 * k] = *(const uint2*)(b3 + BOT + 2 * k);
    }
#pragma unroll
    for (int dw = 0; dw < 2; dw++) {             // pair A (px 4g,4g+1), pair B (+2,+3)
        h2 n0 = uh(ut[dw]);
        h2 n1 = uh(algn(ut[(S - 1) / 2 + dw], ut[(S + 1) / 2 + dw]));
        h2 n2 = uh(ut[S + dw]);
        h2 n7 = uh(um[dw]);
        h2 ct = uh(algn(um[(S - 1) / 2 + dw], um[(S + 1) / 2 + dw]));
        h2 n3 = uh(um[S + dw]);
        h2 n6 = uh(ub[dw]);
        h2 n5 = uh(algn(ub[(S - 1) / 2 + dw], ub[(S + 1) / 2 + dw]));
        h2 n4 = uh(ub[S + dw]);

        h2 T[8];
        T[0] = ct - n0; T[1] = ct - n1; T[2] = ct - n2; T[3] = ct - n3;
        T[4] = ct - n4; T[5] = ct - n5; T[6] = ct - n6; T[7] = ct - n7;
        h2 Sm[4];
#pragma unroll
        for (int k = 0; k < 4; k++) Sm[k] = T[k] + T[k + 4];

        h2 w10 = uh(wt[0]), w11 = uh(wt[1]), w12 = uh(wt[2]);
        h2 w13x2 = uh(wt[3]), bb1 = uh(wt[4]);

        h2 R4[4];
#pragma unroll
        for (int mm = 0; mm < 4; mm++) {
            h2 r = Sm[(mm + 2) & 3] * w12 + bb1;
            r = Sm[(mm + 3) & 3] * w11 + r;
            r = Sm[(mm + 1) & 3] * w10 + r;
            R4[mm] = r;
        }
        h2 h8[8];
#pragma unroll
        for (int k = 0; k < 8; k++)
            h8[k] = (T[(k + 4) & 7] * w13x2 + R4[k & 3]) * T[k];
        sort8_h2(h8);

        h2 acc = uh(wt[13]);
#pragma unroll
        for (int k = 0; k < 8; k++) acc += h8[k] * uh(wt[5 + k]);
        if (dw == 0) *outA = acc; else *outB = acc;
    }
}

__device__ __forceinline__ unsigned tail_px(h2* bh, const unsigned* __restrict__ wtab,
                                            int c, float bsc, float bbi) {
    sort4_h2(bh);
    h2 yv = bh[0] * uh(wtab[1024 + (c << 2)]);
#pragma unroll
    for (int k = 1; k < 4; k++) yv = bh[k] * uh(wtab[1024 + (c << 2) + k]) + yv;
    float zx = fmaf((float)yv.x, bsc, bbi);
    float zy = fmaf((float)yv.y, bsc, bbi);
    float sx = zx / (1.f + __expf(-zx));
    float sy = zy / (1.f + __expf(-zy));
    return __builtin_bit_cast(unsigned, __floats2half2_rn(sx, sy));
}

__device__ __forceinline__ void store_crow(unsigned* convt, int ty0, int tx0,
                                           int row, int g, const unsigned* dwc,
                                           h2 a1A, h2 a1B, h2 a3A, h2 a3B,
                                           h2 a5A, h2 a5B, h2 a7A, h2 a7B) {
    int iy = ty0 - 7 + row;
    bool rin = (unsigned)iy < 256u;
    int ix0 = tx0 - 7 + 4 * g;
    unsigned mA = (rin && (unsigned)ix0 < 256u ? 0x0000FFFFu : 0u)
                | (rin && (unsigned)(ix0 + 1) < 256u ? 0xFFFF0000u : 0u);
    unsigned mB = (rin && (unsigned)(ix0 + 2) < 256u ? 0x0000FFFFu : 0u)
                | (rin && (unsigned)(ix0 + 3) < 256u ? 0xFFFF0000u : 0u);
    int o = row * CTS + 2 * g;
    uint2 s3 = {hu(a3A + uh(dwc[85])) & mA, hu(a3B + uh(dwc[85])) & mB};
    uint2 s7 = {hu(a7A + uh(dwc[87])) & mA, hu(a7B + uh(dwc[87])) & mB};
    *(uint2*)&convt[CTP + o]     = s3;
    *(uint2*)&convt[3 * CTP + o] = s7;
    convt[o + 1]                 = hu(a1A + uh(dwc[84])) & mA;
    convt[o + 2]                 = hu(a1B + uh(dwc[84])) & mB;
    convt[2 * CTP + o + 1]       = hu(a5A + uh(dwc[86])) & mA;
    convt[2 * CTP + o + 2]       = hu(a5B + uh(dwc[86])) & mB;
}

__global__ __launch_bounds__(1024, 8) void k_fused(const __half* __restrict__ xh,
    const unsigned* __restrict__ wtab,
    const float* __restrict__ bns, const float* __restrict__ bnb,
    __half* __restrict__ y16) {

    const int by  = blockIdx.y;                  // b*16 + c
    const int c   = by & 15;
    const int ty0 = (blockIdx.x >> 2) * 64;
    const int tx0 = (blockIdx.x & 3) * 64;
    const int tid = threadIdx.x;

    __shared__ __align__(16) unsigned lxh[84 * LXS];    // fp16 x-tile, rows ty0-10..+73
    __shared__ __align__(16) unsigned convt[4 * CTP];   // conv planes, rows ty0-7..+70

    // ---- stage: 84 rows x 21 uint2 (b64 LDS writes) ----
    {
        const unsigned* xp32 = (const unsigned*)(xh + (size_t)by * HW);
#pragma unroll
        for (int it = 0; it < 2; it++) {
            int t = tid + it * 1024;
            if (it == 0 || t < 84 * 21) {
                int r = t / 21, j = t - r * 21;
                int gy = ty0 - 10 + r;
                int gp = tx0 - 10 + 4 * j;
                unsigned v0 = 0, v1 = 0;
                if ((unsigned)gy < 256u) {
                    const unsigned* rp = xp32 + (gy << 7);
                    if ((unsigned)gp < 256u)       v0 = rp[gp >> 1];
                    if ((unsigned)(gp + 2) < 256u) v1 = rp[(gp >> 1) + 1];
                }
                uint2 st = {v0, v1};
                *(uint2*)&lxh[r * LXS + 2 * j] = st;
            }
        }
    }
    __syncthreads();

    // ---- depthwise convs: 39 row-pairs x 20 col-groups = 780 units, single pass ----
    {
        const unsigned* dwc = wtab + 2048 + c * 96;   // block-uniform -> s_load
        if (tid < 780) {
            int rp_ = tid / 20, g = tid - rp_ * 20;
            int r0 = rp_ * 2;                         // output rows r0, r0+1
            h2 z = {0, 0};
            h2 a7A0 = z, a7B0 = z, a5A0 = z, a5B0 = z, a3A0 = z, a3B0 = z, a1A0 = z, a1B0 = z;
            h2 a7A1 = z, a7B1 = z, a5A1 = z, a5B1 = z, a3A1 = z, a3B1 = z, a1A1 = z, a1B1 = z;
#pragma unroll
            for (int a = 0; a < 8; a++) {
                const unsigned* rrp = lxh + (r0 + a) * LXS + 2 * g;
                uint2 w0 = *(const uint2*)rrp;
                uint2 w1 = *(const uint2*)(rrp + 2);
                uint2 w2 = *(const uint2*)(rrp + 4);
                unsigned u0 = w0.x, u1 = w0.y, u2 = w1.x, u3 = w1.y, u4 = w2.x;
                h2 E[9] = {uh(u0), uh(algn(u0, u1)), uh(u1), uh(algn(u1, u2)),
                           uh(u2), uh(algn(u2, u3)), uh(u3), uh(algn(u3, u4)), uh(u4)};
                if (a < 7) {                          // taps for output row r0
#pragma unroll
                    for (int b = 0; b < 7; b++) {
                        h2 wv = uh(dwc[a * 7 + b]);
                        a7A0 = E[b] * wv + a7A0;  a7B0 = E[b + 2] * wv + a7B0;
                    }
                    if (a >= 1 && a <= 5) {
#pragma unroll
                        for (int b = 0; b < 5; b++) {
                            h2 wv = uh(dwc[49 + (a - 1) * 5 + b]);
                            a5A0 = E[b + 1] * wv + a5A0;  a5B0 = E[b + 3] * wv + a5B0;
                        }
                    }
                    if (a >= 2 && a <= 4) {
#pragma unroll
                        for (int b = 0; b < 3; b++) {
                            h2 wv = uh(dwc[74 + (a - 2) * 3 + b]);
                            a3A0 = E[b + 2] * wv + a3A0;  a3B0 = E[b + 4] * wv + a3B0;
                        }
                    }
                    if (a == 3) {
                        h2 wv = uh(dwc[83]);
                        a1A0 = E[3] * wv;  a1B0 = E[5] * wv;
                    }
                }
                if (a >= 1) {                         // taps for output row r0+1
                    const int ar = a - 1;
#pragma unroll
                    for (int b = 0; b < 7; b++) {
                        h2 wv = uh(dwc[ar * 7 + b]);
                        a7A1 = E[b] * wv + a7A1;  a7B1 = E[b + 2] * wv + a7B1;
                    }
                    if (ar >= 1 && ar <= 5) {
#pragma unroll
                        for (int b = 0; b < 5; b++) {
                            h2 wv = uh(dwc[49 + (ar - 1) * 5 + b]);
                            a5A1 = E[b + 1] * wv + a5A1;  a5B1 = E[b + 3] * wv + a5B1;
                        }
                    }
                    if (ar >= 2 && ar <= 4) {
#pragma unroll
                        for (int b = 0; b < 3; b++) {
                            h2 wv = uh(dwc[74 + (ar - 2) * 3 + b]);
                            a3A1 = E[b + 2] * wv + a3A1;  a3B1 = E[b + 4] * wv + a3B1;
                        }
                    }
                    if (ar == 3) {
                        h2 wv = uh(dwc[83]);
                        a1A1 = E[3] * wv;  a1B1 = E[5] * wv;
                    }
                }
            }
            store_crow(convt, ty0, tx0, r0,     g, dwc, a1A0, a1B0, a3A0, a3B0, a5A0, a5B0, a7A0, a7B0);
            store_crow(convt, ty0, tx0, r0 + 1, g, dwc, a1A1, a1B1, a3A1, a3B1, a5A1, a5B1, a7A1, a7B1);
        }
    }
    __syncthreads();

    // ---- machinery: one 4-px group per thread, single-base constexpr-offset reads ----
    const int R = tid >> 4;                      // 0..63
    const int g = tid & 15;                      // px 4g..4g+3
    const unsigned* b3 = convt + R * CTS + 2 * g;

    h2 bhA[4], bhB[4];
    branch_pair<1, 1, 0>(b3, wtab + ((c << 2) + 0) * 16, &bhA[0], &bhB[0]);
    branch_pair<3, 0, 1>(b3, wtab + ((c << 2) + 1) * 16, &bhA[1], &bhB[1]);
    branch_pair<5, 1, 2>(b3, wtab + ((c << 2) + 2) * 16, &bhA[2], &bhB[2]);
    branch_pair<7, 0, 3>(b3, wtab + ((c << 2) + 3) * 16, &bhA[3], &bhB[3]);

    const float bsc = bns[c], bbi = bnb[c];
    unsigned r0 = tail_px(bhA, wtab, c, bsc, bbi);
    unsigned r1 = tail_px(bhB, wtab, c, bsc, bbi);
    uint2 st = {r0, r1};
    *(uint2*)&y16[(size_t)by * HW + (ty0 + R) * 256 + tx0 + 4 * g] = st;
}

// ---------------- K3: final 1x1 16 -> 1 + sigmoid, 4 px/thread (unchanged) ----------------
__global__ __launch_bounds__(256) void k_final(const __half* __restrict__ y16,
                                               const float* __restrict__ fw,
                                               const float* __restrict__ fb,
                                               float* __restrict__ out) {
    long t  = (long)blockIdx.x * 256 + threadIdx.x;
    long p0 = t * 4;
    int  b  = (int)(p0 >> 16);
    int  hw = (int)(p0 & 65535);

    float bv = fb[0];
    float a0 = bv, a1 = bv, a2 = bv, a3 = bv;
#pragma unroll
    for (int cc = 0; cc < 16; cc++) {
        uint2 u = *(const uint2*)(y16 + (size_t)(b * 16 + cc) * HW + hw);
        float2 v0 = __half22float2(__builtin_bit_cast(__half2, u.x));
        float2 v1 = __half22float2(__builtin_bit_cast(__half2, u.y));
        float wv = fw[cc];
        a0 = fmaf(v0.x, wv, a0);
        a1 = fmaf(v0.y, wv, a1);
        a2 = fmaf(v1.x, wv, a2);
        a3 = fmaf(v1.y, wv, a3);
    }
    float4 r;
    r.x = 1.f / (1.f + __expf(-a0));
    r.y = 1.f / (1.f + __expf(-a1));
    r.z = 1.f / (1.f + __expf(-a2));
    r.w = 1.f / (1.f + __expf(-a3));
    *(float4*)(out + p0) = r;
}

extern "C" void kernel_launch(void* const* d_in, const int* in_sizes, int n_in,
                              void* d_out, int out_size, void* d_ws, size_t ws_size,
                              hipStream_t stream) {
    (void)in_sizes; (void)n_in; (void)out_size; (void)ws_size;
    const float* cen   = (const float*)d_in[0];
    // d_in[1] = mas (unused by the reference)
    const float* in_w  = (const float*)d_in[2];
    const float* in_b  = (const float*)d_in[3];
    const float* dw_w1 = (const float*)d_in[4];
    const float* dw_b1 = (const float*)d_in[5];
    const float* dw_w3 = (const float*)d_in[6];
    const float* dw_b3 = (const float*)d_in[7];
    const float* dw_w5 = (const float*)d_in[8];
    const float* dw_b5 = (const float*)d_in[9];
    const float* dw_w7 = (const float*)d_in[10];
    const float* dw_b7 = (const float*)d_in[11];
    const float* l1w   = (const float*)d_in[12];
    const float* l1b   = (const float*)d_in[13];
    const float* l2w   = (const float*)d_in[14];
    const float* l2b   = (const float*)d_in[15];
    const float* bw    = (const float*)d_in[16];
    const float* bns   = (const float*)d_in[17];
    const float* bnb   = (const float*)d_in[18];
    const float* fw    = (const float*)d_in[19];
    const float* fb    = (const float*)d_in[20];

    // workspace: xh (16.78 MB) | wtab (16 KB) | y16 (16.78 MB)
    __half*   xh   = (__half*)d_ws;
    unsigned* wtab = (unsigned*)((char*)d_ws + (size_t)16777216);
    __half*   y16  = (__half*)((char*)d_ws + (size_t)16777216 + 16384);
    float*    out  = (float*)d_out;

    k_inconv<<<1024, 256, 0, stream>>>(cen, in_w, in_b,
                                       l1w, l1b, l2w, l2b, bw,
                                       dw_w1, dw_b1, dw_w3, dw_b3,
                                       dw_w5, dw_b5, dw_w7, dw_b7, wtab, xh);
    k_fused<<<dim3(16, 128), 1024, 0, stream>>>(xh, wtab, bns, bnb, y16);
    k_final<<<512, 256, 0, stream>>>(y16, fw, fb, out);
}